// Round 8
// baseline (128841.638 us; speedup 1.0000x reference)
//
#include <hip/hip_runtime.h>

#define NP 262144
#define DI 128
#define KCL 512
#define NIT 10

// Fast-math-immune fp32 NaN test.
__device__ __forceinline__ bool isnan_bits32(float x) {
  unsigned b = __float_as_uint(x);
  return (b & 0x7FFFFFFFu) > 0x7F800000u;
}

// numpy pairwise_sum of v[i]*v[i] for n=128 (numpy's 8-accumulator unrolled path):
//   r[j] = a[j];  for i=8,16,...,120: r[j] += a[i+j];
//   res = ((r0+r1)+(r2+r3)) + ((r4+r5)+(r6+r7))
// where a[i] = fl(v[i]*v[i]) (X*X materialized first, then summed).
__device__ __forceinline__ float np_pairwise128_sq(const float* v) {
  float r[8];
  #pragma unroll
  for (int j = 0; j < 8; ++j) r[j] = __fmul_rn(v[j], v[j]);
  #pragma unroll
  for (int t = 1; t < 16; ++t)
    #pragma unroll
    for (int j = 0; j < 8; ++j)
      r[j] = __fadd_rn(r[j], __fmul_rn(v[8 * t + j], v[8 * t + j]));
  float t01 = __fadd_rn(r[0], r[1]), t23 = __fadd_rn(r[2], r[3]);
  float t45 = __fadd_rn(r[4], r[5]), t67 = __fadd_rn(r[6], r[7]);
  return __fadd_rn(__fadd_rn(t01, t23), __fadd_rn(t45, t67));
}

// ---------------- init: C0 = X[:512]; cnorm[k] = np-pairwise of c*c ----------------
__global__ void k_init(const float* __restrict__ X, float* __restrict__ C,
                       float* __restrict__ cnorm) {
  int k = blockIdx.x, d = threadIdx.x;          // 512 blocks x 128 threads
  float v = X[(size_t)k * DI + d];
  C[(size_t)k * DI + d] = v;
  __shared__ float row[DI];
  row[d] = v;
  __syncthreads();
  if (d == 0) cnorm[k] = np_pairwise128_sq(row);
}

// ---------------- assignment: fp32, numpy ordering; np.argmin semantics ----------------
// xn/cc: numpy pairwise (8-acc). dot: sequential-k FMA chain (OpenBLAS micro-kernel).
// s = (xn - 2*dot) + cn, left to right. First-NaN wins (early-break); else strict-<.
__global__ void k_assign_s(const float* __restrict__ X, const float* __restrict__ C,
                           const float* __restrict__ cnorm, int* __restrict__ labels) {
  const int p = blockIdx.x * 256 + threadIdx.x;
  const float4* X4 = (const float4*)X;
  float x[DI];
  #pragma unroll
  for (int q = 0; q < DI / 4; ++q) {
    float4 v = X4[(size_t)p * (DI / 4) + q];
    x[q * 4 + 0] = v.x; x[q * 4 + 1] = v.y;
    x[q * 4 + 2] = v.z; x[q * 4 + 3] = v.w;
  }
  float xn = np_pairwise128_sq(x);

  float best = 0.0f;
  int bestk = -1;
  int firstnan = 0x7fffffff;
  for (int k = 0; k < KCL; ++k) {
    const float* Ck = C + (size_t)k * DI;
    float acc = 0.0f;
    #pragma unroll
    for (int d = 0; d < DI; ++d) acc = __fmaf_rn(x[d], Ck[d], acc);
    float s = __fadd_rn(__fsub_rn(xn, __fmul_rn(2.0f, acc)), cnorm[k]);
    if (isnan_bits32(s)) {
      if (firstnan == 0x7fffffff) firstnan = k;   // first NaN column wins (np early-break)
    } else if (bestk < 0 || s < best) {           // strict <: first of ties
      best = s; bestk = k;
    }
  }
  labels[p] = (firstnan != 0x7fffffff) ? firstnan : bestk;
}

// ---------------- update: block = cluster, thread = dim; ascending-i fp32 adds ----------------
// np.add.at order (i = 0..N-1 ascending). fp32 divide. Empty -> quiet NaN.
// cnorm[k]: numpy pairwise over the new centroid row.
__global__ void k_update_s(const float* __restrict__ X, const int* __restrict__ labels,
                           float* __restrict__ C, float* __restrict__ cnorm) {
  const int k = blockIdx.x, d = threadIdx.x;    // 512 blocks x 128 threads
  __shared__ int lab[128];
  float acc = 0.0f;
  int cnt = 0;
  for (int base = 0; base < NP; base += 128) {
    __syncthreads();
    lab[d] = labels[base + d];
    __syncthreads();
    for (int j = 0; j < 128; ++j) {
      if (lab[j] == k) {                         // wave-uniform branch
        acc = __fadd_rn(acc, X[(size_t)(base + j) * DI + d]);
        ++cnt;
      }
    }
  }
  float cv;
  if (cnt == 0) cv = __uint_as_float(0x7FC00000u);   // quiet NaN, like fp32 0/0
  else cv = __fdiv_rn(acc, (float)cnt);
  C[(size_t)k * DI + d] = cv;
  __shared__ float row[DI];
  row[d] = cv;
  __syncthreads();
  if (d == 0) cnorm[k] = np_pairwise128_sq(row);
}

extern "C" void kernel_launch(void* const* d_in, const int* in_sizes, int n_in,
                              void* d_out, int out_size, void* d_ws, size_t ws_size,
                              hipStream_t stream) {
  (void)in_sizes; (void)n_in; (void)out_size; (void)ws_size;
  const float* X = (const float*)d_in[0];
  int* out = (int*)d_out;
  char* ws = (char*)d_ws;
  float* C     = (float*)(ws);                          // 256 KB
  float* cnorm = (float*)(ws + (size_t)KCL * DI * 4);   // 2 KB

  k_init<<<KCL, DI, 0, stream>>>(X, C, cnorm);
  for (int t = 0; t < NIT; ++t) {
    k_assign_s<<<NP / 256, 256, 0, stream>>>(X, C, cnorm, out);
    if (t < NIT - 1) k_update_s<<<KCL, DI, 0, stream>>>(X, out, C, cnorm);
  }
}

// Round 9
// 13423.125 us; speedup vs baseline: 9.5985x; 9.5985x over previous
//
#include <hip/hip_runtime.h>

#define NP 262144
#define DI 128
#define KCL 512
#define NIT 10
#define NCH 1024      // chunks for the counting sort
#define CHS 256       // points per chunk (NCH*CHS == NP)

// Fast-math-immune fp32 NaN test.
__device__ __forceinline__ bool isnan_bits32(float x) {
  unsigned b = __float_as_uint(x);
  return (b & 0x7FFFFFFFu) > 0x7F800000u;
}

// numpy pairwise_sum of v[i]*v[i] for n=128 (numpy's 8-accumulator unrolled path):
//   r[j] = a[j];  for i=8..120 step 8: r[j] += a[i+j];
//   res = ((r0+r1)+(r2+r3)) + ((r4+r5)+(r6+r7))
__device__ __forceinline__ float np_pairwise128_sq(const float* v) {
  float r[8];
  #pragma unroll
  for (int j = 0; j < 8; ++j) r[j] = __fmul_rn(v[j], v[j]);
  #pragma unroll
  for (int t = 1; t < 16; ++t)
    #pragma unroll
    for (int j = 0; j < 8; ++j)
      r[j] = __fadd_rn(r[j], __fmul_rn(v[8 * t + j], v[8 * t + j]));
  float t01 = __fadd_rn(r[0], r[1]), t23 = __fadd_rn(r[2], r[3]);
  float t45 = __fadd_rn(r[4], r[5]), t67 = __fadd_rn(r[6], r[7]);
  return __fadd_rn(__fadd_rn(t01, t23), __fadd_rn(t45, t67));
}

// ---------------- init: C0 = X[:512]; cnorm[k] = np-pairwise of c*c ----------------
__global__ void k_init(const float* __restrict__ X, float* __restrict__ C,
                       float* __restrict__ cnorm) {
  int k = blockIdx.x, d = threadIdx.x;
  float v = X[(size_t)k * DI + d];
  C[(size_t)k * DI + d] = v;
  __shared__ float row[DI];
  row[d] = v;
  __syncthreads();
  if (d == 0) cnorm[k] = np_pairwise128_sq(row);
}

// ---------------- assignment (unchanged from the passing R7 kernel) ----------------
__global__ void k_assign_s(const float* __restrict__ X, const float* __restrict__ C,
                           const float* __restrict__ cnorm, int* __restrict__ labels) {
  const int p = blockIdx.x * 256 + threadIdx.x;
  const float4* X4 = (const float4*)X;
  float x[DI];
  #pragma unroll
  for (int q = 0; q < DI / 4; ++q) {
    float4 v = X4[(size_t)p * (DI / 4) + q];
    x[q * 4 + 0] = v.x; x[q * 4 + 1] = v.y;
    x[q * 4 + 2] = v.z; x[q * 4 + 3] = v.w;
  }
  float xn = np_pairwise128_sq(x);

  float best = 0.0f;
  int bestk = -1;
  int firstnan = 0x7fffffff;
  for (int k = 0; k < KCL; ++k) {
    const float* Ck = C + (size_t)k * DI;
    float acc = 0.0f;
    #pragma unroll
    for (int d = 0; d < DI; ++d) acc = __fmaf_rn(x[d], Ck[d], acc);
    float s = __fadd_rn(__fsub_rn(xn, __fmul_rn(2.0f, acc)), cnorm[k]);
    if (isnan_bits32(s)) {
      if (firstnan == 0x7fffffff) firstnan = k;
    } else if (bestk < 0 || s < best) {
      best = s; bestk = k;
    }
  }
  labels[p] = (firstnan != 0x7fffffff) ? firstnan : bestk;
}

// ======== deterministic counting-sort update (bit-identical ascending-i adds) ========

// U1: per-chunk histogram, transposed layout counts[k][c].
__global__ void k_hist(const int* __restrict__ labels, int* __restrict__ counts) {
  __shared__ int hist[KCL];
  int c = blockIdx.x, t = threadIdx.x;           // 1024 blocks x 256 threads
  hist[t] = 0; hist[t + 256] = 0;
  __syncthreads();
  int lab = labels[c * CHS + t];
  atomicAdd(&hist[lab], 1);                      // LDS atomic; counts only
  __syncthreads();
  counts[(size_t)t * NCH + c] = hist[t];
  counts[(size_t)(t + 256) * NCH + c] = hist[t + 256];
}

// U2: per-k exclusive scan over chunks -> cbase[k][c]; total[k].
__global__ void k_scan_chunks(const int* __restrict__ counts, int* __restrict__ cbase,
                              int* __restrict__ total) {
  __shared__ int s[NCH];
  int k = blockIdx.x, c = threadIdx.x;           // 512 blocks x 1024 threads
  int v = counts[(size_t)k * NCH + c];
  s[c] = v;
  __syncthreads();
  for (int off = 1; off < NCH; off <<= 1) {
    int t = (c >= off) ? s[c - off] : 0;
    __syncthreads();
    s[c] += t;
    __syncthreads();
  }
  cbase[(size_t)k * NCH + c] = s[c] - v;         // exclusive
  if (c == NCH - 1) total[k] = s[c];
}

// U3: exclusive scan of total[k] -> offset[k]. One block of 512.
__global__ void k_scan_k(const int* __restrict__ total, int* __restrict__ offset) {
  __shared__ int s[KCL];
  int c = threadIdx.x;
  int v = total[c];
  s[c] = v;
  __syncthreads();
  for (int off = 1; off < KCL; off <<= 1) {
    int t = (c >= off) ? s[c - off] : 0;
    __syncthreads();
    s[c] += t;
    __syncthreads();
  }
  offset[c] = s[c] - v;
}

// U4: stable scatter -> list holds point indices grouped by cluster, ascending i.
__global__ void k_scatter(const int* __restrict__ labels, const int* __restrict__ cbase,
                          const int* __restrict__ offset, int* __restrict__ list) {
  __shared__ int lab[CHS];
  int c = blockIdx.x, t = threadIdx.x;           // 1024 blocks x 256 threads
  int L = labels[c * CHS + t];
  lab[t] = L;
  __syncthreads();
  int rank = 0;
  for (int j = 0; j < t; ++j) rank += (lab[j] == L);
  list[offset[L] + cbase[(size_t)L * NCH + c] + rank] = c * CHS + t;
}

// U5: block = cluster, thread = dim; sum rows in list order (== ascending i).
// Adds strictly sequential (bit-identical to the serial scan); loads pipeline freely.
__global__ void k_sum(const float* __restrict__ X, const int* __restrict__ list,
                      const int* __restrict__ offset, const int* __restrict__ total,
                      float* __restrict__ C, float* __restrict__ cnorm) {
  int k = blockIdx.x, d = threadIdx.x;           // 512 blocks x 128 threads
  int n = total[k], off = offset[k];
  float acc = 0.0f;
  int t = 0;
  for (; t + 4 <= n; t += 4) {
    int i0 = list[off + t + 0], i1 = list[off + t + 1];
    int i2 = list[off + t + 2], i3 = list[off + t + 3];
    float x0 = X[(size_t)i0 * DI + d], x1 = X[(size_t)i1 * DI + d];
    float x2 = X[(size_t)i2 * DI + d], x3 = X[(size_t)i3 * DI + d];
    acc = __fadd_rn(acc, x0); acc = __fadd_rn(acc, x1);
    acc = __fadd_rn(acc, x2); acc = __fadd_rn(acc, x3);
  }
  for (; t < n; ++t) {
    int i = list[off + t];
    acc = __fadd_rn(acc, X[(size_t)i * DI + d]);
  }
  float cv = (n == 0) ? __uint_as_float(0x7FC00000u) : __fdiv_rn(acc, (float)n);
  C[(size_t)k * DI + d] = cv;
  __shared__ float row[DI];
  row[d] = cv;
  __syncthreads();
  if (d == 0) cnorm[k] = np_pairwise128_sq(row);
}

extern "C" void kernel_launch(void* const* d_in, const int* in_sizes, int n_in,
                              void* d_out, int out_size, void* d_ws, size_t ws_size,
                              hipStream_t stream) {
  (void)in_sizes; (void)n_in; (void)out_size; (void)ws_size;
  const float* X = (const float*)d_in[0];
  int* out = (int*)d_out;
  char* ws = (char*)d_ws;
  float* C      = (float*)(ws);                              // 256 KB
  float* cnorm  = (float*)(ws + 262144);                     // 2 KB
  int*   counts = (int*)(ws + 264192);                       // 2 MB  [k][c]
  int*   cbase  = (int*)(ws + 264192 + 2097152);             // 2 MB  [k][c]
  int*   total  = (int*)(ws + 264192 + 2 * 2097152);         // 2 KB
  int*   offset = (int*)(ws + 264192 + 2 * 2097152 + 2048);  // 2 KB
  int*   list   = (int*)(ws + 264192 + 2 * 2097152 + 4096);  // 1 MB
  // total ws footprint ~5.3 MB

  k_init<<<KCL, DI, 0, stream>>>(X, C, cnorm);
  for (int t = 0; t < NIT; ++t) {
    k_assign_s<<<NP / 256, 256, 0, stream>>>(X, C, cnorm, out);
    if (t < NIT - 1) {
      k_hist<<<NCH, CHS, 0, stream>>>(out, counts);
      k_scan_chunks<<<KCL, NCH, 0, stream>>>(counts, cbase, total);
      k_scan_k<<<1, KCL, 0, stream>>>(total, offset);
      k_scatter<<<NCH, CHS, 0, stream>>>(out, cbase, offset, list);
      k_sum<<<KCL, DI, 0, stream>>>(X, list, offset, total, C, cnorm);
    }
  }
}